// Round 9
// baseline (236.166 us; speedup 1.0000x reference)
//
#include <hip/hip_runtime.h>
#include <math.h>

#define LAG 168
#define HOR 24
#define DM 6
#define FFD 18
#define NL 3
#define LNEPS 1e-5f

typedef unsigned int u32;
typedef float f32x4 __attribute__((ext_vector_type(4)));
typedef float f32x16 __attribute__((ext_vector_type(16)));
typedef short s16x8 __attribute__((ext_vector_type(8)));
typedef __bf16 bfx2 __attribute__((ext_vector_type(2)));

// Per-wave LDS slice (4-byte word offsets). One wave per block -> in-order
// LDS pipe, no barriers; overlays are same-wave-safe.
//   ZB   4 zero words: hi-lane fragment reads (k=8..15 padding) land here.
//   HB   h bf16 [192 rows][8] (d0-5, d6=1.0 bias col, d7=0). Dead after the
//        6 QKV MFMAs -> overlaid by O-stage bf16 [192][8] (same geometry).
//   VT   V^T bf16 [7][200] pitch 100 words; row 6 = ones (softmax denom).
//        Dead after vf build.
//   QB   Q bf16 [192][8] (q*cQ, d6,7 = 0).
//   KB   K bf16 [192][8]. Dead after kf build -> PP repack (576 w) overlays.
//   end  hf fp32 [192][6] for the head overlays words 0..1151.
#define ZB    0
#define HB    4
#define VT    772
#define QB    1472
#define KB    2240
#define PPb   2240
#define SLICE 3008   // 12032 B/wave -> 13 blocks/CU
#define HBH   (2*HB)
#define VTH   (2*VT)

__device__ __forceinline__ u32 pkbf(float a, float b) {
    bfx2 t; t[0] = (__bf16)a; t[1] = (__bf16)b;
    return __builtin_bit_cast(u32, t);
}
__device__ __forceinline__ s16x8 mk8(u32 a, u32 b, u32 c, u32 d) {
    uint4 u; u.x = a; u.y = b; u.z = c; u.w = d;
    return __builtin_bit_cast(s16x8, u);
}
__device__ __forceinline__ float b2f(unsigned short h) {
    u32 u = ((u32)h) << 16; return __builtin_bit_cast(float, u);
}
__device__ __forceinline__ void ln6(const float* r, const float* g, const float* bb, float* outv) {
    float m = (r[0]+r[1]+r[2]+r[3]+r[4]+r[5]) * (1.0f/6.0f);
    float v = 0.f;
#pragma unroll
    for (int d = 0; d < DM; ++d) { float t = r[d]-m; v += t*t; }
    v *= (1.0f/6.0f);
    float rs = __builtin_amdgcn_rsqf(v + LNEPS);
#pragma unroll
    for (int d = 0; d < DM; ++d) outv[d] = (r[d]-m)*rs*g[d] + bb[d];
}

// No min-waves clause: a binding VGPR cap demotes fragment arrays to scratch
// (R4/R5: FETCH 742/567 MB, 2x slower). Target natural alloc <= 64 regs.
__global__ __launch_bounds__(64) void tfenc_kernel(
    const float* __restrict__ input, const float* __restrict__ pos_emb,
    const float* __restrict__ ipw, const float* __restrict__ ipb,
    const float* __restrict__ ow,  const float* __restrict__ obp,
    const float* __restrict__ l1g, const float* __restrict__ l1b,
    const float* __restrict__ f1w, const float* __restrict__ f1b,
    const float* __restrict__ f2w, const float* __restrict__ f2b,
    const float* __restrict__ l2g, const float* __restrict__ l2b,
    const float* __restrict__ hw,  const float* __restrict__ hb,
    float* __restrict__ out)
{
    __shared__ __align__(16) float lds[SLICE];
    float*  sl  = lds;
    __bf16* slh = (__bf16*)sl;
    u32*    slu = (u32*)sl;

    const int L = threadIdx.x;
    const int b = blockIdx.x;

    if (L < 4) slu[ZB + L] = 0;   // zero block (never overwritten until head)

    float hv[3][DM];
#pragma unroll
    for (int i = 0; i < 3; ++i) {
        int r = L + 64*i;
        bool real = (r < LAG);
        hv[i][0] = real ? input[(size_t)b*LAG + r] : 0.f;
#pragma unroll
        for (int j = 0; j < 5; ++j)
            hv[i][1+j] = real ? pos_emb[r*5 + j] : 0.f;
    }
    // initial h -> HB (bias column = 1)
#pragma unroll
    for (int i = 0; i < 3; ++i) {
        int r = L + 64*i;
        uint4 hw4;
        hw4.x = pkbf(hv[i][0], hv[i][1]);
        hw4.y = pkbf(hv[i][2], hv[i][3]);
        hw4.z = pkbf(hv[i][4], hv[i][5]);
        hw4.w = pkbf(1.0f, 0.0f);
        *(uint4*)(slu + HB + 4*r) = hw4;
    }

    const float cQ = 0.5889116917845058f;  // log2(e)/sqrt(6)
    const bool lo = (L < 32);
    const int  rB = L & 31;
    const int  tstep = lo ? 128 : 0;       // hi lanes stay on the zero block

#pragma unroll 1
    for (int il = 0; il < NL; ++il) {
        const float* Wip = ipw + il*3*DM*DM;
        const float* bip = ipb + il*3*DM;
        const float* Wo  = ow  + il*DM*DM;
        const float* bo  = obp + il*DM;
        const float* g1  = l1g + il*DM;     const float* c1  = l1b + il*DM;
        const float* W1  = f1w + il*FFD*DM; const float* bb1 = f1b + il*FFD;
        const float* W2  = f2w + il*DM*FFD; const float* bb2 = f2b + il*DM;
        const float* g2  = l2g + il*DM;     const float* c2  = l2b + il*DM;

        // ---- A_qkv fragment: A[e][d0-5] = W (q-rows pre-scaled by cQ),
        //      A[e][6] = bias, A[e][7..15] = 0; rows e>=18 and hi lanes = 0.
        s16x8 aq;
        {
            int m  = rB;
            int mm = (m < 18) ? m : 0;
            const float* wrow = Wip + mm*6;
            float w0 = wrow[0], w1 = wrow[1], w2 = wrow[2];
            float w3 = wrow[3], w4 = wrow[4], w5 = wrow[5];
            float bm = bip[mm];
            float s  = (m < 6) ? cQ : 1.0f;
            u32 hm = (lo && m < 18) ? ~0u : 0u;
            aq = mk8(pkbf(w0*s, w1*s) & hm, pkbf(w2*s, w3*s) & hm,
                     pkbf(w4*s, w5*s) & hm, pkbf(bm*s, 0.f) & hm);
        }

        // ---- QKV projection: one 32x32x16 MFMA per 32 rows ----
        const u32* hbp = slu + (lo ? (HB + 4*rB) : ZB);
#pragma unroll
        for (int t = 0; t < 6; ++t) {
            s16x8 hbf = __builtin_bit_cast(s16x8, *(const uint4*)(hbp + tstep*t));
            const f32x16 z = {};
            f32x16 c = __builtin_amdgcn_mfma_f32_32x32x16_bf16(aq, hbf, z, 0, 0, 0);
            int r = rB + 32*t;
            if (lo) {
                // lo lane: q0-3 (regs 0-3), k2-5 (regs 4-7), v4,v5 (regs 8,9)
                uint2 qw; qw.x = pkbf(c[0], c[1]); qw.y = pkbf(c[2], c[3]);
                *(uint2*)(slu + QB + 4*r) = qw;
                slu[KB + 4*r + 1] = pkbf(c[4], c[5]);
                slu[KB + 4*r + 2] = pkbf(c[6], c[7]);
                slh[VTH + 4*200 + r] = (__bf16)c[8];
                slh[VTH + 5*200 + r] = (__bf16)c[9];
            } else {
                // hi lane: q4,q5 (regs 0,1), k0,k1 (regs 2,3), v0-3 (regs 4-7)
                uint2 qw; qw.x = pkbf(c[0], c[1]); qw.y = 0u;
                *(uint2*)(slu + QB + 4*r + 2) = qw;
                slu[KB + 4*r + 0] = pkbf(c[2], c[3]);
                slu[KB + 4*r + 3] = 0u;
                slh[VTH + 0*200 + r] = (__bf16)c[4];
                slh[VTH + 1*200 + r] = (__bf16)c[5];
                slh[VTH + 2*200 + r] = (__bf16)c[6];
                slh[VTH + 3*200 + r] = (__bf16)c[7];
            }
        }
        // ones row = softmax denominator column (V^T row 6)
        {
            __bf16 one = (__bf16)1.0f;
            slh[VTH + 6*200 + L]       = one;
            slh[VTH + 6*200 + 64 + L]  = one;
            slh[VTH + 6*200 + 128 + L] = one;
        }

        // ---- K fragments (A of 32x32x16): b128 reads; hi lanes = zero block
        s16x8 kf[6];
        {
            const u32* kbp = slu + (lo ? (KB + 4*rB) : ZB);
#pragma unroll
            for (int kt = 0; kt < 6; ++kt)
                kf[kt] = __builtin_bit_cast(s16x8, *(const uint4*)(kbp + tstep*kt));
        }
        // ---- V fragments (B of 16x16x32), register-cached for the layer ----
        s16x8 vf[6];
        {
            int d = L & 15;
            int vrow = d < 7 ? d : 6;            // d>=7 feeds discarded cols
            const u32* vb = slu + (VT + vrow*100 + (L >> 4)*4);
#pragma unroll
            for (int kc = 0; kc < 6; ++kc)
                vf[kc] = __builtin_bit_cast(s16x8, *(const uint4*)(vb + kc*16));
        }

        const int wrbase = PPb + (L & 31)*18 + 2*(L >> 5);
        const int rdbase = PPb + (L & 15)*18 + 4*(L >> 4);
        const u32* qbp = slu + (lo ? (QB + 4*rB) : ZB);

        // ---- attention: S^T = K*Q^T (32x32), exp2, LDS repack, P*V (16x16) ----
#pragma unroll
        for (int qt = 0; qt < 6; ++qt) {
            s16x8 qf = __builtin_bit_cast(s16x8, *(const uint4*)(qbp + tstep*qt));
            f32x4 acc0 = {0.f,0.f,0.f,0.f};
            f32x4 acc1 = {0.f,0.f,0.f,0.f};
#pragma unroll
            for (int kt = 0; kt < 6; ++kt) {
                const f32x16 z = {};
                f32x16 S = __builtin_amdgcn_mfma_f32_32x32x16_bf16(kf[kt], qf, z, 0, 0, 0);
                u32 w[8];
#pragma unroll
                for (int jj = 0; jj < 8; ++jj) {
                    if (kt == 5 && jj >= 2) w[jj] = 0u;   // keys >= 168 masked
                    else w[jj] = pkbf(__builtin_amdgcn_exp2f(S[2*jj]),
                                      __builtin_amdgcn_exp2f(S[2*jj+1]));
                }
                u32* ppw = slu + wrbase;
                { uint2 t2; t2.x=w[0]; t2.y=w[1]; *(uint2*)(ppw     ) = t2; }
                { uint2 t2; t2.x=w[2]; t2.y=w[3]; *(uint2*)(ppw +  4) = t2; }
                { uint2 t2; t2.x=w[4]; t2.y=w[5]; *(uint2*)(ppw +  8) = t2; }
                { uint2 t2; t2.x=w[6]; t2.y=w[7]; *(uint2*)(ppw + 12) = t2; }
                const u32* rr = slu + rdbase;
                uint2 a00 = *(const uint2*)(rr);
                uint2 a01 = *(const uint2*)(rr + 2);
                uint2 a10 = *(const uint2*)(rr + 288);
                uint2 a11 = *(const uint2*)(rr + 290);
                acc0 = __builtin_amdgcn_mfma_f32_16x16x32_bf16(mk8(a00.x,a00.y,a01.x,a01.y), vf[kt], acc0, 0,0,0);
                acc1 = __builtin_amdgcn_mfma_f32_16x16x32_bf16(mk8(a10.x,a10.y,a11.x,a11.y), vf[kt], acc1, 0,0,0);
            }
            // stage O tiles to bf16 over the dead HB region
            int d = L & 15;
            if (d < 7) {
                int qb = 32*qt + 4*(L >> 4);
#pragma unroll
                for (int r2 = 0; r2 < 4; ++r2) {
                    slh[HBH + (qb + r2)*8 + d]      = (__bf16)acc0[r2];
                    slh[HBH + (qb + 16 + r2)*8 + d] = (__bf16)acc1[r2];
                }
            }
        }

        // ---- epilogue per owned row: normalize, out-proj, LN, FF, LN ----
#pragma unroll
        for (int i = 0; i < 3; ++i) {
            int r = L + 64*i;
            s16x8 ov = __builtin_bit_cast(s16x8, *(const uint4*)(slh + HBH + r*8));
            float o[7];
#pragma unroll
            for (int d = 0; d < 7; ++d) o[d] = b2f((unsigned short)ov[d]);
            float inv = __builtin_amdgcn_rcpf(o[6]);
            float att[6], rv[6];
#pragma unroll
            for (int d = 0; d < 6; ++d) att[d] = o[d]*inv;
#pragma unroll
            for (int e = 0; e < 6; ++e) {
                float a = bo[e];
#pragma unroll
                for (int d = 0; d < 6; ++d) a += att[d]*Wo[e*6+d];
                rv[e] = hv[i][e] + a;
            }
            ln6(rv, g1, c1, hv[i]);
            float o2[6];
#pragma unroll
            for (int d = 0; d < 6; ++d) o2[d] = bb2[d];
#pragma unroll
            for (int ff = 0; ff < FFD; ++ff) {
                float a = bb1[ff];
#pragma unroll
                for (int d = 0; d < 6; ++d) a += hv[i][d]*W1[ff*6+d];
                a = fmaxf(a, 0.f);
#pragma unroll
                for (int d = 0; d < 6; ++d) o2[d] += a*W2[d*FFD+ff];
            }
#pragma unroll
            for (int d = 0; d < 6; ++d) rv[d] = hv[i][d] + o2[d];
            ln6(rv, g2, c2, hv[i]);
            if (il < 2) {
                // write next layer's h row (overwrites this row's O slot,
                // which only this lane reads -- done above)
                uint4 hw4;
                hw4.x = pkbf(hv[i][0], hv[i][1]);
                hw4.y = pkbf(hv[i][2], hv[i][3]);
                hw4.z = pkbf(hv[i][4], hv[i][5]);
                hw4.w = pkbf(1.0f, 0.0f);
                *(uint4*)(slu + HB + 4*r) = hw4;
            }
        }
    }

    // ---- final residual+relu -> hf fp32 [192][6] at slice base ----
#pragma unroll
    for (int i = 0; i < 3; ++i) {
        int r = L + 64*i;
        bool real = (r < LAG);
        float x0 = real ? input[(size_t)b*LAG + r] : 0.f;
        sl[r*6 + 0] = real ? fmaxf(hv[i][0] + x0, 0.f) : 0.f;
#pragma unroll
        for (int j = 0; j < 5; ++j) {
            float xj = real ? pos_emb[r*5 + j] : 0.f;
            sl[r*6 + 1 + j] = real ? fmaxf(hv[i][1+j] + xj, 0.f) : 0.f;
        }
    }
    // head: 48 lanes, lane = 2*t + half; each dots 504 contiguous elements
    {
        int t = L >> 1, half = L & 1;
        float p = 0.f;
        if (L < 48) {
            const float4* wv  = (const float4*)(hw + (size_t)t*1008 + half*504);
            const float4* hv4 = (const float4*)(sl + half*504);
#pragma unroll 6
            for (int k = 0; k < 126; ++k) {
                float4 w = wv[k], hh = hv4[k];
                p += w.x*hh.x + w.y*hh.y + w.z*hh.z + w.w*hh.w;
            }
        }
        p += __shfl_xor(p, 1);
        if (L < 48 && half == 0)
            out[(size_t)b*HOR + t] = p + hb[t];
    }
}

extern "C" void kernel_launch(void* const* d_in, const int* in_sizes, int n_in,
                              void* d_out, int out_size, void* d_ws, size_t ws_size,
                              hipStream_t stream) {
    const float* input   = (const float*)d_in[0];
    const float* pos_emb = (const float*)d_in[1];
    const float* ipw     = (const float*)d_in[2];
    const float* ipb     = (const float*)d_in[3];
    const float* ow      = (const float*)d_in[4];
    const float* ob      = (const float*)d_in[5];
    const float* l1g     = (const float*)d_in[6];
    const float* l1b     = (const float*)d_in[7];
    const float* f1w     = (const float*)d_in[8];
    const float* f1b     = (const float*)d_in[9];
    const float* f2w     = (const float*)d_in[10];
    const float* f2b     = (const float*)d_in[11];
    const float* l2g     = (const float*)d_in[12];
    const float* l2b     = (const float*)d_in[13];
    const float* hw      = (const float*)d_in[14];
    const float* hb      = (const float*)d_in[15];
    float* out = (float*)d_out;

    const int B = in_sizes[0] / LAG;
    tfenc_kernel<<<dim3(B), dim3(64), 0, stream>>>(
        input, pos_emb, ipw, ipb, ow, ob, l1g, l1b,
        f1w, f1b, f2w, f2b, l2g, l2b, hw, hb, out);
}